// Round 2
// baseline (327.879 us; speedup 1.0000x reference)
//
#include <hip/hip_runtime.h>
#include <math.h>

// Problem constants (from reference): B=32, A=3, S=52, C=80
constexpr int NCELL = 32 * 3 * 52 * 52;   // 259584
constexpr int PS = 85;                    // prediction channels (5 + C)
constexpr int NC = 80;                    // classes

// Accumulator layout in d_ws (6 floats):
// 0: sum bce over noobj | 1: n_noobj | 2: sum obj_term | 3: n_obj
// 4: sum box_se | 5: sum nll

// 16-byte packed load type with only 4-byte alignment guarantee (rows are
// 340 B = 85 dwords, so row bases are 4B-aligned only). AMDGPU supports
// dword-aligned dwordx4 global loads.
struct __attribute__((packed, aligned(4))) F4 { float x, y, z, w; };

__global__ __launch_bounds__(256) void yolo_main(const float* __restrict__ pred,
                                                 const float* __restrict__ tgt,
                                                 float* __restrict__ acc)
{
    // 4 lanes per cell: lane group g=0..3 handles logits [g*20, g*20+20).
    int tid  = blockIdx.x * 256 + threadIdx.x;
    int cell = tid >> 2;          // NCELL = 259584 = 64 cells/block * 4056 blocks exactly
    int g    = tid & 3;

    float s0 = 0.f, s1 = 0.f, s2 = 0.f, s3 = 0.f, s4 = 0.f, s5 = 0.f;

    const float* row  = pred + cell * PS;
    const float* trow = tgt  + cell * 6;

    // --- load this lane's 20 logits (channels 5 + g*20 ...) ---
    float x[20];
    const F4* lp = (const F4*)(row + 5 + g * 20);
    #pragma unroll
    for (int j = 0; j < 5; ++j) {
        F4 v = lp[j];
        x[4*j+0] = v.x; x[4*j+1] = v.y; x[4*j+2] = v.z; x[4*j+3] = v.w;
    }

    float t5f = trow[5];
    int   lbl = (int)t5f;

    // --- pass 1: group max over 80 logits ---
    float m = x[0];
    #pragma unroll
    for (int k = 1; k < 20; ++k) m = fmaxf(m, x[k]);
    m = fmaxf(m, __shfl_xor(m, 1));
    m = fmaxf(m, __shfl_xor(m, 2));

    // --- pass 2: exp-sum + label-logit select (compile-time reg indices) ---
    float se = 0.f, sel = 0.f;
    #pragma unroll
    for (int k = 0; k < 20; ++k) {
        se += __expf(x[k] - m);
        if (g * 20 + k == lbl) sel = x[k];
    }
    se  += __shfl_xor(se, 1);
    se  += __shfl_xor(se, 2);
    sel += __shfl_xor(sel, 1);
    sel += __shfl_xor(sel, 2);

    // --- lane 0 of each group: box/obj/bce scalar math + accumulation ---
    if (g == 0) {
        F4 pv = *(const F4*)row;              // p0..p3
        float p0 = pv.x, p1 = pv.y, p2 = pv.z, p3 = pv.w;
        float p4 = row[4];
        F4 tv = *(const F4*)trow;             // t0..t3
        float t0 = tv.x, t1 = tv.y, t2 = tv.z, t3 = tv.w;
        float t4 = trow[4];

        bool obj   = (t0 == 1.0f);
        bool noobj = (t0 == 0.0f);

        // BCE-with-logits on objectness
        float bce = fmaxf(p0, 0.0f) - p0 * t0 + log1pf(__expf(-fabsf(p0)));

        // midpoint IoU: b1 = pred[0:4], b2 = target[1:5]
        float b1x1 = p0 - p2 * 0.5f, b1y1 = p1 - p3 * 0.5f;
        float b1x2 = p0 + p2 * 0.5f, b1y2 = p1 + p3 * 0.5f;
        float b2x1 = t1 - t3 * 0.5f, b2y1 = t2 - t4 * 0.5f;
        float b2x2 = t1 + t3 * 0.5f, b2y2 = t2 + t4 * 0.5f;
        float xi1 = fmaxf(b1x1, b2x1), yi1 = fmaxf(b1y1, b2y1);
        float xi2 = fminf(b1x2, b2x2), yi2 = fminf(b1y2, b2y2);
        float inter = fmaxf(xi2 - xi1, 0.0f) * fmaxf(yi2 - yi1, 0.0f);
        float a1 = fabsf((b1x2 - b1x1) * (b1y2 - b1y1));
        float a2 = fabsf((b2x2 - b2x1) * (b2y2 - b2y1));
        float iou = inter / (a1 + a2 - inter + 1e-6f);

        // object loss term
        float pobj = 1.0f / (1.0f + __expf(-p0));
        float dob  = pobj - iou * t0;
        float objterm = dob * dob;

        // box loss term (sigmoid on pred[1:5])
        float d1 = 1.0f / (1.0f + __expf(-p1)) - t1;
        float d2 = 1.0f / (1.0f + __expf(-p2)) - t2;
        float d3 = 1.0f / (1.0f + __expf(-p3)) - t3;
        float d4 = 1.0f / (1.0f + __expf(-p4)) - t4;
        float boxse = d1*d1 + d2*d2 + d3*d3 + d4*d4;

        // class NLL
        float nll = __logf(se) - (sel - m);

        if (noobj) { s0 = bce; s1 = 1.0f; }
        if (obj)   { s2 = objterm; s3 = 1.0f; s4 = boxse; s5 = nll; }
    }

    // --- wave (64-lane) reduction ---
    #pragma unroll
    for (int off = 32; off > 0; off >>= 1) {
        s0 += __shfl_down(s0, off);
        s1 += __shfl_down(s1, off);
        s2 += __shfl_down(s2, off);
        s3 += __shfl_down(s3, off);
        s4 += __shfl_down(s4, off);
        s5 += __shfl_down(s5, off);
    }

    // --- cross-wave reduction in LDS ---
    __shared__ float red[4][6];
    int lane = threadIdx.x & 63;
    int wid  = threadIdx.x >> 6;
    if (lane == 0) {
        red[wid][0] = s0; red[wid][1] = s1; red[wid][2] = s2;
        red[wid][3] = s3; red[wid][4] = s4; red[wid][5] = s5;
    }
    __syncthreads();
    if (threadIdx.x == 0) {
        float a0=0,a1=0,a2=0,a3=0,a4=0,a5=0;
        #pragma unroll
        for (int w = 0; w < 4; ++w) {
            a0 += red[w][0]; a1 += red[w][1]; a2 += red[w][2];
            a3 += red[w][3]; a4 += red[w][4]; a5 += red[w][5];
        }
        atomicAdd(&acc[0], a0);
        atomicAdd(&acc[1], a1);
        atomicAdd(&acc[2], a2);
        atomicAdd(&acc[3], a3);
        atomicAdd(&acc[4], a4);
        atomicAdd(&acc[5], a5);
    }
}

__global__ void yolo_final(const float* __restrict__ acc, float* __restrict__ out)
{
    if (threadIdx.x == 0 && blockIdx.x == 0) {
        float n_noobj = acc[1];
        float n_obj   = acc[3];
        // return order: (5*box, 1*object, 0.5*noobj, 1*class)
        out[0] = 5.0f * acc[4] / fmaxf(n_obj * 4.0f, 1.0f);
        out[1] = 1.0f * acc[2] / fmaxf(n_obj, 1.0f);
        out[2] = 0.5f * acc[0] / fmaxf(n_noobj, 1.0f);
        out[3] = 1.0f * acc[5] / fmaxf(n_obj, 1.0f);
    }
}

extern "C" void kernel_launch(void* const* d_in, const int* in_sizes, int n_in,
                              void* d_out, int out_size, void* d_ws, size_t ws_size,
                              hipStream_t stream)
{
    const float* pred = (const float*)d_in[0];
    const float* tgt  = (const float*)d_in[1];
    float* out = (float*)d_out;
    float* acc = (float*)d_ws;

    hipMemsetAsync(acc, 0, 6 * sizeof(float), stream);

    // 4 lanes/cell, 64 cells per 256-thread block; 259584/64 = 4056 exactly.
    int grid = NCELL / 64;
    yolo_main<<<grid, 256, 0, stream>>>(pred, tgt, acc);
    yolo_final<<<1, 64, 0, stream>>>(acc, out);
}

// Round 3
// 182.765 us; speedup vs baseline: 1.7940x; 1.7940x over previous
//
#include <hip/hip_runtime.h>
#include <math.h>

// Problem constants (from reference): B=32, A=3, S=52, C=80
constexpr int NCELL = 32 * 3 * 52 * 52;   // 259584 = 128 * 2028
constexpr int PS = 85;                    // prediction channels (5 + C)
constexpr int NC = 80;                    // classes

constexpr int CPB = 128;                  // cells per block (= threads per block)
constexpr int TPB = 128;
constexpr int PRED_DW = CPB * PS;         // 10880 dwords
constexpr int PRED_V4 = PRED_DW / 4;      // 2720 float4
constexpr int PRED_FULL_IT = PRED_V4 / TPB;          // 21
constexpr int PRED_TAIL = PRED_V4 - PRED_FULL_IT * TPB; // 32
constexpr int TGT_DW = CPB * 6;           // 768 dwords
constexpr int TGT_V4 = TGT_DW / 4;        // 192 float4

// Accumulator layout in d_ws (6 floats):
// 0: sum bce over noobj | 1: n_noobj | 2: sum obj_term | 3: n_obj
// 4: sum box_se | 5: sum nll

__global__ __launch_bounds__(TPB) void yolo_main(const float* __restrict__ pred,
                                                 const float* __restrict__ tgt,
                                                 float* __restrict__ acc)
{
    __shared__ float sp[PRED_DW];   // 43520 B
    __shared__ float st[TGT_DW];    // 3072 B
    __shared__ float red[2][6];

    int tid = threadIdx.x;
    long long blockCell = (long long)blockIdx.x * CPB;

    // ---- stage: flat coalesced float4 copy of this block's chunk ----
    // pred chunk base = blockCell*85 dwords = blockIdx*43520 B (16B aligned).
    const float4* gp = (const float4*)(pred + blockCell * PS);
    const float4* gt = (const float4*)(tgt  + blockCell * 6);
    float4* sp4 = (float4*)sp;
    float4* st4 = (float4*)st;

    #pragma unroll
    for (int it = 0; it < PRED_FULL_IT; ++it)
        sp4[tid + it * TPB] = gp[tid + it * TPB];
    if (tid < PRED_TAIL)
        sp4[tid + PRED_FULL_IT * TPB] = gp[tid + PRED_FULL_IT * TPB];

    st4[tid] = gt[tid];                       // first 128 of 192
    if (tid < TGT_V4 - TPB)                   // remaining 64
        st4[TPB + tid] = gt[TPB + tid];

    __syncthreads();

    // ---- compute: one thread per cell, reads from LDS ----
    // Row stride 85 dwords is odd -> bank index (21*i + ch) mod 32 is a
    // permutation across 32 lanes -> conflict-free (2-way wave64 = free).
    const float* row = sp + tid * PS;
    const float* t   = st + tid * 6;

    float t0 = t[0], t1 = t[1], t2 = t[2], t3 = t[3], t4 = t[4];
    int   lbl = (int)t[5];

    bool obj   = (t0 == 1.0f);
    bool noobj = (t0 == 0.0f);

    float p0 = row[0], p1 = row[1], p2 = row[2], p3 = row[3], p4 = row[4];

    // BCE-with-logits on objectness
    float bce = fmaxf(p0, 0.0f) - p0 * t0 + log1pf(__expf(-fabsf(p0)));

    // midpoint IoU: b1 = pred[0:4], b2 = target[1:5]
    float b1x1 = p0 - p2 * 0.5f, b1y1 = p1 - p3 * 0.5f;
    float b1x2 = p0 + p2 * 0.5f, b1y2 = p1 + p3 * 0.5f;
    float b2x1 = t1 - t3 * 0.5f, b2y1 = t2 - t4 * 0.5f;
    float b2x2 = t1 + t3 * 0.5f, b2y2 = t2 + t4 * 0.5f;
    float xi1 = fmaxf(b1x1, b2x1), yi1 = fmaxf(b1y1, b2y1);
    float xi2 = fminf(b1x2, b2x2), yi2 = fminf(b1y2, b2y2);
    float inter = fmaxf(xi2 - xi1, 0.0f) * fmaxf(yi2 - yi1, 0.0f);
    float a1 = fabsf((b1x2 - b1x1) * (b1y2 - b1y1));
    float a2 = fabsf((b2x2 - b2x1) * (b2y2 - b2y1));
    float iou = inter / (a1 + a2 - inter + 1e-6f);

    // object loss term
    float pobj = 1.0f / (1.0f + __expf(-p0));
    float dob  = pobj - iou * t0;
    float objterm = dob * dob;

    // box loss term (sigmoid on pred[1:5])
    float d1 = 1.0f / (1.0f + __expf(-p1)) - t1;
    float d2 = 1.0f / (1.0f + __expf(-p2)) - t2;
    float d3 = 1.0f / (1.0f + __expf(-p3)) - t3;
    float d4 = 1.0f / (1.0f + __expf(-p4)) - t4;
    float boxse = d1*d1 + d2*d2 + d3*d3 + d4*d4;

    // class NLL: two passes over 80 logits in LDS
    float m = row[5];
    #pragma unroll 8
    for (int c = 1; c < NC; ++c) m = fmaxf(m, row[5 + c]);
    float se = 0.0f;
    #pragma unroll 8
    for (int c = 0; c < NC; ++c) se += __expf(row[5 + c] - m);
    float sel = row[5 + lbl];
    float nll = __logf(se) - (sel - m);

    float s0 = 0.f, s1 = 0.f, s2 = 0.f, s3 = 0.f, s4 = 0.f, s5 = 0.f;
    if (noobj) { s0 = bce; s1 = 1.0f; }
    if (obj)   { s2 = objterm; s3 = 1.0f; s4 = boxse; s5 = nll; }

    // ---- wave (64-lane) reduction ----
    #pragma unroll
    for (int off = 32; off > 0; off >>= 1) {
        s0 += __shfl_down(s0, off);
        s1 += __shfl_down(s1, off);
        s2 += __shfl_down(s2, off);
        s3 += __shfl_down(s3, off);
        s4 += __shfl_down(s4, off);
        s5 += __shfl_down(s5, off);
    }

    // ---- cross-wave reduction (2 waves) ----
    int lane = tid & 63;
    int wid  = tid >> 6;
    if (lane == 0) {
        red[wid][0] = s0; red[wid][1] = s1; red[wid][2] = s2;
        red[wid][3] = s3; red[wid][4] = s4; red[wid][5] = s5;
    }
    __syncthreads();
    if (tid == 0) {
        float a0 = red[0][0] + red[1][0];
        float a1 = red[0][1] + red[1][1];
        float a2 = red[0][2] + red[1][2];
        float a3 = red[0][3] + red[1][3];
        float a4 = red[0][4] + red[1][4];
        float a5 = red[0][5] + red[1][5];
        atomicAdd(&acc[0], a0);
        atomicAdd(&acc[1], a1);
        atomicAdd(&acc[2], a2);
        atomicAdd(&acc[3], a3);
        atomicAdd(&acc[4], a4);
        atomicAdd(&acc[5], a5);
    }
}

__global__ void yolo_final(const float* __restrict__ acc, float* __restrict__ out)
{
    if (threadIdx.x == 0 && blockIdx.x == 0) {
        float n_noobj = acc[1];
        float n_obj   = acc[3];
        // return order: (5*box, 1*object, 0.5*noobj, 1*class)
        out[0] = 5.0f * acc[4] / fmaxf(n_obj * 4.0f, 1.0f);
        out[1] = 1.0f * acc[2] / fmaxf(n_obj, 1.0f);
        out[2] = 0.5f * acc[0] / fmaxf(n_noobj, 1.0f);
        out[3] = 1.0f * acc[5] / fmaxf(n_obj, 1.0f);
    }
}

extern "C" void kernel_launch(void* const* d_in, const int* in_sizes, int n_in,
                              void* d_out, int out_size, void* d_ws, size_t ws_size,
                              hipStream_t stream)
{
    const float* pred = (const float*)d_in[0];
    const float* tgt  = (const float*)d_in[1];
    float* out = (float*)d_out;
    float* acc = (float*)d_ws;

    hipMemsetAsync(acc, 0, 6 * sizeof(float), stream);

    int grid = NCELL / CPB;   // 2028, exact
    yolo_main<<<grid, TPB, 0, stream>>>(pred, tgt, acc);
    yolo_final<<<1, 64, 0, stream>>>(acc, out);
}